// Round 4
// baseline (429.805 us; speedup 1.0000x reference)
//
#include <hip/hip_runtime.h>
#include <hip/hip_cooperative_groups.h>
#include <math.h>

namespace cg = cooperative_groups;

#define BATCH  8
#define SEQ    8192
#define DMODEL 256
#define DSTATE 2
#define CHUNKS 256   // C
#define CLEN   32    // L = SEQ / C

// ---------------------------------------------------------------------------
// Layouts:
//   x, y : [B][T][D] fp32
//   params: [D][S] fp32 (S=2)
//   E / Hin workspace: [B][C][1024] floats
//     lane d4 = d/4 owns 16 floats: j=0..3 -> (s0re, s0im, s1re, s1im)
//     scan slot r = d4*8 + j*2 + s -> float2 at offset 2r within the 1024 block.
// Recurrence: h[t] = a h[t-1] + B x[t], a = e^{lm}(cos ph + i sin ph)
// y[t,d] = sum_s Re(C h) + D_diag x
// ---------------------------------------------------------------------------

// =================== Fused cooperative kernel =============================
// 512 blocks x 256 threads = 2048 waves; wave w -> (b = w>>8, c = w&255).
// Needs only 2 co-resident blocks/CU (8 waves/CU) -> coop capacity check
// passes with margin (R3's 2048x64 at exactly-8-blocks/CU was rejected).
// Phase 3 re-reads x: 64 MB fits the 256 MiB L3 and is warm from phase 1.
__global__ void __launch_bounds__(256, 2)
ssm_fused(const float* __restrict__ x,
          const float* __restrict__ lam,
          const float* __restrict__ aph,
          const float* __restrict__ Bre,
          const float* __restrict__ Bim,
          const float* __restrict__ Cre,
          const float* __restrict__ Cim,
          const float* __restrict__ Dd,
          float* __restrict__ E,
          float* __restrict__ Hin,
          float* __restrict__ y) {
    const int lane = threadIdx.x & 63;
    const int w = blockIdx.x * 4 + (threadIdx.x >> 6);   // wave id = b*CHUNKS + c
    const int b = w >> 8;
    const int c = w & (CHUNKS - 1);
    const int d0 = lane * 4;

    float ar[4][2], ai[4][2], br[4][2], bi[4][2];
#pragma unroll
    for (int j = 0; j < 4; ++j) {
        const int d = d0 + j;
#pragma unroll
        for (int s = 0; s < 2; ++s) {
            const float lm = lam[d * 2 + s];
            const float ph = aph[d * 2 + s];
            const float m  = expf(lm);
            ar[j][s] = m * cosf(ph);
            ai[j][s] = m * sinf(ph);
            br[j][s] = Bre[d * 2 + s];
            bi[j][s] = Bim[d * 2 + s];
        }
    }

    const float* xp = x + ((size_t)b * SEQ + (size_t)c * CLEN) * DMODEL + d0;

    // --- phase 1: local end state (zero init) ---
    {
        float hr[4][2] = {}, hi[4][2] = {};
#pragma unroll 4
        for (int t = 0; t < CLEN; ++t) {
            const float4 xv = *reinterpret_cast<const float4*>(xp + (size_t)t * DMODEL);
            const float xj[4] = {xv.x, xv.y, xv.z, xv.w};
#pragma unroll
            for (int j = 0; j < 4; ++j) {
#pragma unroll
                for (int s = 0; s < 2; ++s) {
                    const float nr = fmaf(ar[j][s], hr[j][s],
                                     fmaf(-ai[j][s], hi[j][s], br[j][s] * xj[j]));
                    const float ni = fmaf(ar[j][s], hi[j][s],
                                     fmaf( ai[j][s], hr[j][s], bi[j][s] * xj[j]));
                    hr[j][s] = nr;
                    hi[j][s] = ni;
                }
            }
        }
        float* ep = E + ((size_t)w * 64 + lane) * 16;
#pragma unroll
        for (int j = 0; j < 4; ++j) {
            float4 v;
            v.x = hr[j][0]; v.y = hi[j][0];
            v.z = hr[j][1]; v.w = hi[j][1];
            reinterpret_cast<float4*>(ep)[j] = v;
        }
    }

    __threadfence();
    cg::this_grid().sync();

    // --- phase 2: two chunk-scans per wave (4096 scans / 2048 waves) ---
#pragma unroll
    for (int i = 0; i < 2; ++i) {
        const int g = w * 2 + i;             // scan id 0..4095
        const int sb = g >> 9;
        const int r  = g & 511;              // d4*8 + j*2 + s
        const int sd = (r >> 3) * 4 + ((r >> 1) & 3);
        const int ss = r & 1;

        const double lmD = (double)lam[sd * 2 + ss];
        const double phD = (double)aph[sd * 2 + ss];
        const double mL = exp(lmD * (double)CLEN);
        const double pL = phD * (double)CLEN;
        const float Ar = (float)(mL * cos(pL));
        const float Ai = (float)(mL * sin(pL));

        const size_t base = (size_t)sb * CHUNKS * 1024 + (size_t)r * 2;

        float2 e[4];
#pragma unroll
        for (int k = 0; k < 4; ++k) {
            const int cc = lane * 4 + k;
            e[k] = *reinterpret_cast<const float2*>(E + base + (size_t)cc * 1024);
        }

        // local group aggregate: v = A^3 e0 + A^2 e1 + A e2 + e3
        float vr = e[0].x, vi = e[0].y;
#pragma unroll
        for (int k = 1; k < 4; ++k) {
            const float nr = fmaf(Ar, vr, fmaf(-Ai, vi, e[k].x));
            const float ni = fmaf(Ar, vi, fmaf( Ai, vr, e[k].y));
            vr = nr; vi = ni;
        }

        // Kogge-Stone inclusive over 64 lane-groups, W_k = A^(4k) (fp64)
#pragma unroll
        for (int st = 0; st < 6; ++st) {
            const int k = 1 << st;
            const double n = (double)CLEN * 4.0 * (double)k;
            const double mm = exp(lmD * n);
            const double pp = phD * n;
            const float Wr = (float)(mm * cos(pp));
            const float Wi = (float)(mm * sin(pp));
            const float ur = __shfl_up(vr, (unsigned)k);
            const float ui = __shfl_up(vi, (unsigned)k);
            if (lane >= k) {
                vr = fmaf(Wr, ur, fmaf(-Wi, ui, vr));
                vi = fmaf(Wr, ui, fmaf( Wi, ur, vi));
            }
        }

        // exclusive across lane-groups, then sequential within each group
        float pr = __shfl_up(vr, 1);
        float pi = __shfl_up(vi, 1);
        if (lane == 0) { pr = 0.f; pi = 0.f; }

#pragma unroll
        for (int k = 0; k < 4; ++k) {
            const int cc = lane * 4 + k;
            *reinterpret_cast<float2*>(Hin + base + (size_t)cc * 1024) =
                make_float2(pr, pi);
            const float nr = fmaf(Ar, pr, fmaf(-Ai, pi, e[k].x));
            const float ni = fmaf(Ar, pi, fmaf( Ai, pr, e[k].y));
            pr = nr; pi = ni;
        }
    }

    __threadfence();
    cg::this_grid().sync();

    // --- phase 3: replay from Hin seed (x re-read, L3-warm), fused output ---
    float cr[4][2], ci[4][2], dd[4];
#pragma unroll
    for (int j = 0; j < 4; ++j) {
        const int d = d0 + j;
        dd[j] = Dd[d];
#pragma unroll
        for (int s = 0; s < 2; ++s) {
            cr[j][s] = Cre[d * 2 + s];
            ci[j][s] = Cim[d * 2 + s];
        }
    }

    float hr[4][2], hi[4][2];
    const float* hp = Hin + ((size_t)w * 64 + lane) * 16;
#pragma unroll
    for (int j = 0; j < 4; ++j) {
        const float4 v = reinterpret_cast<const float4*>(hp)[j];
        hr[j][0] = v.x; hi[j][0] = v.y;
        hr[j][1] = v.z; hi[j][1] = v.w;
    }

    float* yp = y + ((size_t)b * SEQ + (size_t)c * CLEN) * DMODEL + d0;
#pragma unroll 4
    for (int t = 0; t < CLEN; ++t) {
        const float4 xv = *reinterpret_cast<const float4*>(xp + (size_t)t * DMODEL);
        const float xj[4] = {xv.x, xv.y, xv.z, xv.w};
        float yj[4];
#pragma unroll
        for (int j = 0; j < 4; ++j) {
            float acc = dd[j] * xj[j];
#pragma unroll
            for (int s = 0; s < 2; ++s) {
                const float nr = fmaf(ar[j][s], hr[j][s],
                                 fmaf(-ai[j][s], hi[j][s], br[j][s] * xj[j]));
                const float ni = fmaf(ar[j][s], hi[j][s],
                                 fmaf( ai[j][s], hr[j][s], bi[j][s] * xj[j]));
                hr[j][s] = nr;
                hi[j][s] = ni;
                acc = fmaf(cr[j][s], nr, acc);
                acc = fmaf(-ci[j][s], ni, acc);
            }
            yj[j] = acc;
        }
        float4 yv;
        yv.x = yj[0]; yv.y = yj[1]; yv.z = yj[2]; yv.w = yj[3];
        *reinterpret_cast<float4*>(yp + (size_t)t * DMODEL) = yv;
    }
}

// =================== Fallback: known-passing R2 3-kernel path =============
__global__ void ssm_chunk_state(const float* __restrict__ x,
                                const float* __restrict__ lam,
                                const float* __restrict__ aph,
                                const float* __restrict__ Bre,
                                const float* __restrict__ Bim,
                                float* __restrict__ E) {
    const int lane = threadIdx.x;
    const int bid  = blockIdx.x;
    const int b = bid / CHUNKS;
    const int c = bid % CHUNKS;
    const int d0 = lane * 4;

    float ar[4][2], ai[4][2], br[4][2], bi[4][2];
#pragma unroll
    for (int j = 0; j < 4; ++j) {
        const int d = d0 + j;
#pragma unroll
        for (int s = 0; s < 2; ++s) {
            const float lm = lam[d * 2 + s];
            const float ph = aph[d * 2 + s];
            const float m  = expf(lm);
            ar[j][s] = m * cosf(ph);
            ai[j][s] = m * sinf(ph);
            br[j][s] = Bre[d * 2 + s];
            bi[j][s] = Bim[d * 2 + s];
        }
    }

    float hr[4][2] = {}, hi[4][2] = {};
    const float* xp = x + ((size_t)b * SEQ + (size_t)c * CLEN) * DMODEL + d0;
#pragma unroll 4
    for (int t = 0; t < CLEN; ++t) {
        const float4 xv = *reinterpret_cast<const float4*>(xp + (size_t)t * DMODEL);
        const float xj[4] = {xv.x, xv.y, xv.z, xv.w};
#pragma unroll
        for (int j = 0; j < 4; ++j) {
#pragma unroll
            for (int s = 0; s < 2; ++s) {
                const float nr = fmaf(ar[j][s], hr[j][s],
                                 fmaf(-ai[j][s], hi[j][s], br[j][s] * xj[j]));
                const float ni = fmaf(ar[j][s], hi[j][s],
                                 fmaf( ai[j][s], hr[j][s], bi[j][s] * xj[j]));
                hr[j][s] = nr;
                hi[j][s] = ni;
            }
        }
    }

    float* ep = E + ((size_t)(b * CHUNKS + c) * 64 + lane) * 16;
#pragma unroll
    for (int j = 0; j < 4; ++j) {
        float4 v;
        v.x = hr[j][0]; v.y = hi[j][0];
        v.z = hr[j][1]; v.w = hi[j][1];
        reinterpret_cast<float4*>(ep)[j] = v;
    }
}

__global__ void ssm_chunk_scan(const float* __restrict__ E,
                               float* __restrict__ Hin,
                               const float* __restrict__ lam,
                               const float* __restrict__ aph) {
    const int lane = threadIdx.x & 63;
    const int g = blockIdx.x * 4 + (threadIdx.x >> 6);
    const int b = g >> 9;
    const int r = g & 511;
    const int d = (r >> 3) * 4 + ((r >> 1) & 3);
    const int s = r & 1;

    const double lm = (double)lam[d * 2 + s];
    const double ph = (double)aph[d * 2 + s];
    const double mL = exp(lm * (double)CLEN);
    const double pL = ph * (double)CLEN;
    const float Ar = (float)(mL * cos(pL));
    const float Ai = (float)(mL * sin(pL));

    const size_t base = (size_t)b * CHUNKS * 1024 + (size_t)r * 2;

    float2 e[4];
#pragma unroll
    for (int i = 0; i < 4; ++i)
        e[i] = *reinterpret_cast<const float2*>(E + base + (size_t)(lane * 4 + i) * 1024);

    float vr = e[0].x, vi = e[0].y;
#pragma unroll
    for (int i = 1; i < 4; ++i) {
        const float nr = fmaf(Ar, vr, fmaf(-Ai, vi, e[i].x));
        const float ni = fmaf(Ar, vi, fmaf( Ai, vr, e[i].y));
        vr = nr; vi = ni;
    }

#pragma unroll
    for (int st = 0; st < 6; ++st) {
        const int k = 1 << st;
        const double n = (double)CLEN * 4.0 * (double)k;
        const double mm = exp(lm * n);
        const double pp = ph * n;
        const float Wr = (float)(mm * cos(pp));
        const float Wi = (float)(mm * sin(pp));
        const float ur = __shfl_up(vr, (unsigned)k);
        const float ui = __shfl_up(vi, (unsigned)k);
        if (lane >= k) {
            vr = fmaf(Wr, ur, fmaf(-Wi, ui, vr));
            vi = fmaf(Wr, ui, fmaf( Wi, ur, vi));
        }
    }

    float pr = __shfl_up(vr, 1);
    float pi = __shfl_up(vi, 1);
    if (lane == 0) { pr = 0.f; pi = 0.f; }

#pragma unroll
    for (int i = 0; i < 4; ++i) {
        *reinterpret_cast<float2*>(Hin + base + (size_t)(lane * 4 + i) * 1024) =
            make_float2(pr, pi);
        const float nr = fmaf(Ar, pr, fmaf(-Ai, pi, e[i].x));
        const float ni = fmaf(Ar, pi, fmaf( Ai, pr, e[i].y));
        pr = nr; pi = ni;
    }
}

__global__ void ssm_output(const float* __restrict__ x,
                           const float* __restrict__ lam,
                           const float* __restrict__ aph,
                           const float* __restrict__ Bre,
                           const float* __restrict__ Bim,
                           const float* __restrict__ Cre,
                           const float* __restrict__ Cim,
                           const float* __restrict__ Dd,
                           const float* __restrict__ Hin,
                           float* __restrict__ y) {
    const int lane = threadIdx.x;
    const int bid  = blockIdx.x;
    const int b = bid / CHUNKS;
    const int c = bid % CHUNKS;
    const int d0 = lane * 4;

    float ar[4][2], ai[4][2], br[4][2], bi[4][2], cr[4][2], ci[4][2], dd[4];
#pragma unroll
    for (int j = 0; j < 4; ++j) {
        const int d = d0 + j;
        dd[j] = Dd[d];
#pragma unroll
        for (int s = 0; s < 2; ++s) {
            const float lm = lam[d * 2 + s];
            const float ph = aph[d * 2 + s];
            const float m  = expf(lm);
            ar[j][s] = m * cosf(ph);
            ai[j][s] = m * sinf(ph);
            br[j][s] = Bre[d * 2 + s];
            bi[j][s] = Bim[d * 2 + s];
            cr[j][s] = Cre[d * 2 + s];
            ci[j][s] = Cim[d * 2 + s];
        }
    }

    float hr[4][2], hi[4][2];
    const float* hp = Hin + ((size_t)(b * CHUNKS + c) * 64 + lane) * 16;
#pragma unroll
    for (int j = 0; j < 4; ++j) {
        const float4 v = reinterpret_cast<const float4*>(hp)[j];
        hr[j][0] = v.x; hi[j][0] = v.y;
        hr[j][1] = v.z; hi[j][1] = v.w;
    }

    const size_t tbase = ((size_t)b * SEQ + (size_t)c * CLEN) * DMODEL + d0;
    const float* xp = x + tbase;
    float* yp = y + tbase;
#pragma unroll 4
    for (int t = 0; t < CLEN; ++t) {
        const float4 xv = *reinterpret_cast<const float4*>(xp + (size_t)t * DMODEL);
        const float xj[4] = {xv.x, xv.y, xv.z, xv.w};
        float yj[4];
#pragma unroll
        for (int j = 0; j < 4; ++j) {
            float acc = dd[j] * xj[j];
#pragma unroll
            for (int s = 0; s < 2; ++s) {
                const float nr = fmaf(ar[j][s], hr[j][s],
                                 fmaf(-ai[j][s], hi[j][s], br[j][s] * xj[j]));
                const float ni = fmaf(ar[j][s], hi[j][s],
                                 fmaf( ai[j][s], hr[j][s], bi[j][s] * xj[j]));
                hr[j][s] = nr;
                hi[j][s] = ni;
                acc = fmaf(cr[j][s], nr, acc);
                acc = fmaf(-ci[j][s], ni, acc);
            }
            yj[j] = acc;
        }
        float4 yv;
        yv.x = yj[0]; yv.y = yj[1]; yv.z = yj[2]; yv.w = yj[3];
        *reinterpret_cast<float4*>(yp + (size_t)t * DMODEL) = yv;
    }
}

extern "C" void kernel_launch(void* const* d_in, const int* in_sizes, int n_in,
                              void* d_out, int out_size, void* d_ws, size_t ws_size,
                              hipStream_t stream) {
    const float* x   = (const float*)d_in[0];
    const float* lam = (const float*)d_in[1];
    const float* aph = (const float*)d_in[2];
    const float* Bre = (const float*)d_in[3];
    const float* Bim = (const float*)d_in[4];
    const float* Cre = (const float*)d_in[5];
    const float* Cim = (const float*)d_in[6];
    const float* Dd  = (const float*)d_in[7];
    float* yo = (float*)d_out;

    float* E   = (float*)d_ws;                                  // 8 MB
    float* Hin = E + (size_t)BATCH * CHUNKS * 1024;             // 8 MB

    void* args[] = {
        (void*)&x, (void*)&lam, (void*)&aph, (void*)&Bre, (void*)&Bim,
        (void*)&Cre, (void*)&Cim, (void*)&Dd, (void*)&E, (void*)&Hin,
        (void*)&yo,
    };
    hipError_t err = hipLaunchCooperativeKernel(
        reinterpret_cast<void*>(ssm_fused),
        dim3(BATCH * CHUNKS / 4), dim3(256), args, 0, stream);

    if (err != hipSuccess) {
        (void)hipGetLastError();   // clear sticky error, take the 3-kernel path
        ssm_chunk_state<<<BATCH * CHUNKS, 64, 0, stream>>>(x, lam, aph, Bre, Bim, E);
        ssm_chunk_scan<<<(BATCH * 512) / 4, 256, 0, stream>>>(E, Hin, lam, aph);
        ssm_output<<<BATCH * CHUNKS, 64, 0, stream>>>(x, lam, aph, Bre, Bim,
                                                      Cre, Cim, Dd, Hin, yo);
    }
}

// Round 6
// 167.987 us; speedup vs baseline: 2.5586x; 2.5586x over previous
//
#include <hip/hip_runtime.h>
#include <math.h>

#define BATCH  8
#define SEQ    8192
#define DMODEL 256
#define DSTATE 2
#define CHUNKS 256   // C
#define CLEN   32    // L = SEQ / C
#define CPAD   1040  // floats per (b,c) block: 1024 data + 16 pad
                     // -> lane stride 4160 B in K2 (breaks 4 KB channel conflict),
                     //    still 16 B aligned (4160 = 260*16)

typedef float floatx4 __attribute__((ext_vector_type(4)));  // nontemporal-store-safe

// ---------------------------------------------------------------------------
// Layouts:
//   x, y : [B][T][D] fp32
//   params: [D][S] fp32 (S=2)
//   E / Hin workspace: [B][C][CPAD] floats (first 1024 used)
//     lane d4 = d/4 owns 16 floats: j=0..3 -> (s0re, s0im, s1re, s1im)
//     scan slot r = d4*8 + j*2 + s -> float2 at float-offset 2r.
// Recurrence: h[t] = a h[t-1] + B x[t], a = e^{lm}(cos ph + i sin ph)
// y[t,d] = sum_s Re(C h) + D_diag x
// ---------------------------------------------------------------------------

// Kernel 1: per-chunk local end state (zero init).
// grid = BATCH*CHUNKS blocks x 64 threads; block -> (b,c); lane -> d4.
__global__ void ssm_chunk_state(const float* __restrict__ x,
                                const float* __restrict__ lam,
                                const float* __restrict__ aph,
                                const float* __restrict__ Bre,
                                const float* __restrict__ Bim,
                                float* __restrict__ E) {
    const int lane = threadIdx.x;
    const int bid  = blockIdx.x;
    const int b = bid >> 8;
    const int c = bid & (CHUNKS - 1);
    const int d0 = lane * 4;

    float ar[4][2], ai[4][2], br[4][2], bi[4][2];
#pragma unroll
    for (int j = 0; j < 4; ++j) {
        const int d = d0 + j;
#pragma unroll
        for (int s = 0; s < 2; ++s) {
            const float lm = lam[d * 2 + s];
            const float ph = aph[d * 2 + s];
            const float m  = expf(lm);
            ar[j][s] = m * cosf(ph);
            ai[j][s] = m * sinf(ph);
            br[j][s] = Bre[d * 2 + s];
            bi[j][s] = Bim[d * 2 + s];
        }
    }

    float hr[4][2] = {}, hi[4][2] = {};
    const float* xp = x + ((size_t)b * SEQ + (size_t)c * CLEN) * DMODEL + d0;
#pragma unroll 4
    for (int t = 0; t < CLEN; ++t) {
        const float4 xv = *reinterpret_cast<const float4*>(xp + (size_t)t * DMODEL);
        const float xj[4] = {xv.x, xv.y, xv.z, xv.w};
#pragma unroll
        for (int j = 0; j < 4; ++j) {
#pragma unroll
            for (int s = 0; s < 2; ++s) {
                const float nr = fmaf(ar[j][s], hr[j][s],
                                 fmaf(-ai[j][s], hi[j][s], br[j][s] * xj[j]));
                const float ni = fmaf(ar[j][s], hi[j][s],
                                 fmaf( ai[j][s], hr[j][s], bi[j][s] * xj[j]));
                hr[j][s] = nr;
                hi[j][s] = ni;
            }
        }
    }

    float* ep = E + (size_t)bid * CPAD + lane * 16;
#pragma unroll
    for (int j = 0; j < 4; ++j) {
        float4 v;
        v.x = hr[j][0]; v.y = hi[j][0];
        v.z = hr[j][1]; v.w = hi[j][1];
        reinterpret_cast<float4*>(ep)[j] = v;
    }
}

// Kernel 2: wave-parallel scan over chunks; one wave per (b,d,s) scan,
// lane l owns chunks 4l..4l+3. Uniform multiplier A = a^CLEN; Kogge-Stone
// step multipliers A^(4k) in fp64. 1024 blocks x 256 threads = 4096 waves.
__global__ void ssm_chunk_scan(const float* __restrict__ E,
                               float* __restrict__ Hin,
                               const float* __restrict__ lam,
                               const float* __restrict__ aph) {
    const int lane = threadIdx.x & 63;
    const int g = blockIdx.x * 4 + (threadIdx.x >> 6);   // scan id 0..4095
    const int b = g >> 9;
    const int r = g & 511;                               // d4*8 + j*2 + s
    const int d = (r >> 3) * 4 + ((r >> 1) & 3);
    const int s = r & 1;

    const double lm = (double)lam[d * 2 + s];
    const double ph = (double)aph[d * 2 + s];
    const double mL = exp(lm * (double)CLEN);
    const double pL = ph * (double)CLEN;
    const float Ar = (float)(mL * cos(pL));
    const float Ai = (float)(mL * sin(pL));

    const size_t base = (size_t)b * CHUNKS * CPAD + (size_t)r * 2;

    float2 e[4];
#pragma unroll
    for (int i = 0; i < 4; ++i) {
        const int cc = lane * 4 + i;
        e[i] = *reinterpret_cast<const float2*>(E + base + (size_t)cc * CPAD);
    }

    // local group aggregate: v = A^3 e0 + A^2 e1 + A e2 + e3
    float vr = e[0].x, vi = e[0].y;
#pragma unroll
    for (int i = 1; i < 4; ++i) {
        const float nr = fmaf(Ar, vr, fmaf(-Ai, vi, e[i].x));
        const float ni = fmaf(Ar, vi, fmaf( Ai, vr, e[i].y));
        vr = nr; vi = ni;
    }

    // Kogge-Stone inclusive over 64 lane-groups, W_k = A^(4k) (fp64)
#pragma unroll
    for (int st = 0; st < 6; ++st) {
        const int k = 1 << st;
        const double n = (double)CLEN * 4.0 * (double)k;
        const double mm = exp(lm * n);
        const double pp = ph * n;
        const float Wr = (float)(mm * cos(pp));
        const float Wi = (float)(mm * sin(pp));
        const float ur = __shfl_up(vr, (unsigned)k);
        const float ui = __shfl_up(vi, (unsigned)k);
        if (lane >= k) {
            vr = fmaf(Wr, ur, fmaf(-Wi, ui, vr));
            vi = fmaf(Wr, ui, fmaf( Wi, ur, vi));
        }
    }

    // exclusive across lane-groups, then sequential within each group
    float pr = __shfl_up(vr, 1);
    float pi = __shfl_up(vi, 1);
    if (lane == 0) { pr = 0.f; pi = 0.f; }

#pragma unroll
    for (int i = 0; i < 4; ++i) {
        const int cc = lane * 4 + i;
        *reinterpret_cast<float2*>(Hin + base + (size_t)cc * CPAD) =
            make_float2(pr, pi);
        const float nr = fmaf(Ar, pr, fmaf(-Ai, pi, e[i].x));
        const float ni = fmaf(Ar, pi, fmaf( Ai, pr, e[i].y));
        pr = nr; pi = ni;
    }
}

// Kernel 3: replay local recurrence seeded from Hin; fuse output projection.
__global__ void ssm_output(const float* __restrict__ x,
                           const float* __restrict__ lam,
                           const float* __restrict__ aph,
                           const float* __restrict__ Bre,
                           const float* __restrict__ Bim,
                           const float* __restrict__ Cre,
                           const float* __restrict__ Cim,
                           const float* __restrict__ Dd,
                           const float* __restrict__ Hin,
                           float* __restrict__ y) {
    const int lane = threadIdx.x;
    const int bid  = blockIdx.x;
    const int b = bid >> 8;
    const int c = bid & (CHUNKS - 1);
    const int d0 = lane * 4;

    float ar[4][2], ai[4][2], br[4][2], bi[4][2], cr[4][2], ci[4][2], dd[4];
#pragma unroll
    for (int j = 0; j < 4; ++j) {
        const int d = d0 + j;
        dd[j] = Dd[d];
#pragma unroll
        for (int s = 0; s < 2; ++s) {
            const float lm = lam[d * 2 + s];
            const float ph = aph[d * 2 + s];
            const float m  = expf(lm);
            ar[j][s] = m * cosf(ph);
            ai[j][s] = m * sinf(ph);
            br[j][s] = Bre[d * 2 + s];
            bi[j][s] = Bim[d * 2 + s];
            cr[j][s] = Cre[d * 2 + s];
            ci[j][s] = Cim[d * 2 + s];
        }
    }

    float hr[4][2], hi[4][2];
    const float* hp = Hin + (size_t)bid * CPAD + lane * 16;
#pragma unroll
    for (int j = 0; j < 4; ++j) {
        const float4 v = reinterpret_cast<const float4*>(hp)[j];
        hr[j][0] = v.x; hi[j][0] = v.y;
        hr[j][1] = v.z; hi[j][1] = v.w;
    }

    const size_t tbase = ((size_t)b * SEQ + (size_t)c * CLEN) * DMODEL + d0;
    const float* xp = x + tbase;
    float* yp = y + tbase;
#pragma unroll 4
    for (int t = 0; t < CLEN; ++t) {
        const float4 xv = *reinterpret_cast<const float4*>(xp + (size_t)t * DMODEL);
        const float xj[4] = {xv.x, xv.y, xv.z, xv.w};
        float yj[4];
#pragma unroll
        for (int j = 0; j < 4; ++j) {
            float acc = dd[j] * xj[j];
#pragma unroll
            for (int s = 0; s < 2; ++s) {
                const float nr = fmaf(ar[j][s], hr[j][s],
                                 fmaf(-ai[j][s], hi[j][s], br[j][s] * xj[j]));
                const float ni = fmaf(ar[j][s], hi[j][s],
                                 fmaf( ai[j][s], hr[j][s], bi[j][s] * xj[j]));
                hr[j][s] = nr;
                hi[j][s] = ni;
                acc = fmaf(cr[j][s], nr, acc);
                acc = fmaf(-ci[j][s], ni, acc);
            }
            yj[j] = acc;
        }
        floatx4 yv;
        yv.x = yj[0]; yv.y = yj[1]; yv.z = yj[2]; yv.w = yj[3];
        // y is never re-read: nontemporal store keeps x L3-resident.
        __builtin_nontemporal_store(yv,
            reinterpret_cast<floatx4*>(yp + (size_t)t * DMODEL));
    }
}

extern "C" void kernel_launch(void* const* d_in, const int* in_sizes, int n_in,
                              void* d_out, int out_size, void* d_ws, size_t ws_size,
                              hipStream_t stream) {
    const float* x   = (const float*)d_in[0];
    const float* lam = (const float*)d_in[1];
    const float* aph = (const float*)d_in[2];
    const float* Bre = (const float*)d_in[3];
    const float* Bim = (const float*)d_in[4];
    const float* Cre = (const float*)d_in[5];
    const float* Cim = (const float*)d_in[6];
    const float* Dd  = (const float*)d_in[7];
    float* yo = (float*)d_out;

    float* E   = (float*)d_ws;                                    // ~8.5 MB
    float* Hin = E + (size_t)BATCH * CHUNKS * CPAD;               // ~8.5 MB

    ssm_chunk_state<<<BATCH * CHUNKS, 64, 0, stream>>>(x, lam, aph, Bre, Bim, E);
    ssm_chunk_scan<<<(BATCH * 512) / 4, 256, 0, stream>>>(E, Hin, lam, aph);
    ssm_output<<<BATCH * CHUNKS, 64, 0, stream>>>(x, lam, aph, Bre, Bim,
                                                  Cre, Cim, Dd, Hin, yo);
}